// Round 15
// baseline (350.452 us; speedup 1.0000x reference)
//
#include <hip/hip_runtime.h>
#include <hip/hip_fp16.h>

#define D 128
#define EDGE_IN 258

typedef __attribute__((ext_vector_type(8))) short bf16x8;
typedef __attribute__((ext_vector_type(4))) float f32x4;

__device__ __forceinline__ float rl_f(float v, int j) {
  return __int_as_float(__builtin_amdgcn_readlane(__float_as_int(v), j));
}
__device__ __forceinline__ int rl_i(int v, int j) {
  return __builtin_amdgcn_readlane(v, j);
}
__device__ __forceinline__ ushort f32_to_bf16(float f) {
  unsigned u = __float_as_uint(f);
  unsigned r = (u + 0x7FFFu + ((u >> 16) & 1u)) >> 16;  // RNE
  return (ushort)r;
}
__device__ __forceinline__ float bf16_to_f32(ushort h) {
  return __uint_as_float(((unsigned)h) << 16);
}

// ---------------- CSR build ----------------
__global__ void zero_int(int* __restrict__ p, int n) {
  int i = blockIdx.x * blockDim.x + threadIdx.x;
  if (i < n) p[i] = 0;
}

// ILP-4: 4 independent atomic chains per thread (R12: 1/thread was latency-bound)
__global__ void hist_kernel(const int* __restrict__ dst, int* __restrict__ deg, int ne) {
  int base = blockIdx.x * 1024 + threadIdx.x;
#pragma unroll
  for (int k = 0; k < 4; k++) {
    int e = base + k * 256;
    if (e < ne) atomicAdd(&deg[dst[e]], 1);
  }
}

__global__ __launch_bounds__(256) void scan_part(const int* __restrict__ deg,
                                                 int* __restrict__ bsum, int n) {
  __shared__ int red[256];
  int b = blockIdx.x, tid = threadIdx.x;
  int base = b * 1024 + tid * 4;
  int s = 0;
#pragma unroll
  for (int j = 0; j < 4; j++) { int idx = base + j; if (idx < n) s += deg[idx]; }
  red[tid] = s;
  __syncthreads();
  for (int off = 128; off; off >>= 1) {
    if (tid < off) red[tid] += red[tid + off];
    __syncthreads();
  }
  if (tid == 0) bsum[b] = red[0];
}

__global__ __launch_bounds__(256) void scan_bsums(int* __restrict__ bsum, int nb) {
  __shared__ int part[256];
  int tid = threadIdx.x;
  int v = (tid < nb) ? bsum[tid] : 0;
  part[tid] = v;
  __syncthreads();
  for (int off = 1; off < 256; off <<= 1) {
    int t = (tid >= off) ? part[tid - off] : 0;
    __syncthreads();
    part[tid] += t;
    __syncthreads();
  }
  if (tid < nb) bsum[tid] = (tid == 0) ? 0 : part[tid - 1];  // exclusive
}

__global__ __launch_bounds__(256) void scan_final(const int* __restrict__ deg,
                                                  const int* __restrict__ bsumex,
                                                  int* __restrict__ offs,
                                                  int* __restrict__ cur, int n, int ne) {
  __shared__ int part[256];
  int b = blockIdx.x, tid = threadIdx.x;
  int base = b * 1024 + tid * 4;
  int v[4];
  int s = 0;
#pragma unroll
  for (int j = 0; j < 4; j++) {
    int idx = base + j;
    v[j] = (idx < n) ? deg[idx] : 0;
    s += v[j];
  }
  part[tid] = s;
  __syncthreads();
  for (int off = 1; off < 256; off <<= 1) {
    int t = (tid >= off) ? part[tid - off] : 0;
    __syncthreads();
    part[tid] += t;
    __syncthreads();
  }
  int run = bsumex[b] + ((tid == 0) ? 0 : part[tid - 1]);
#pragma unroll
  for (int j = 0; j < 4; j++) {
    int idx = base + j;
    if (idx < n) { offs[idx] = run; cur[idx] = run; run += v[j]; }
  }
  if (b == 0 && tid == 0) offs[n] = ne;
}

// meta 8B/edge: {si, half2(rx,ry)} — halves the random-store line traffic
// (R12 counter: WRITE_SIZE 51MB = 4x payload from 16B scatters). ILP-4 chains.
__global__ void scatter_kernel(const int* __restrict__ dst, const int* __restrict__ srcIdx,
                               const float2* __restrict__ rel, int* __restrict__ cur,
                               int2* __restrict__ meta, int ne) {
  int base = blockIdx.x * 1024 + threadIdx.x;
  int e[4], p[4];
  int2 mv[4];
  int cnt = 0;
#pragma unroll
  for (int k = 0; k < 4; k++) {
    int ek = base + k * 256;
    if (ek < ne) {
      float2 r = rel[ek];
      __half2 h = __floats2half2_rn(r.x, r.y);
      mv[cnt].x = srcIdx[ek];
      mv[cnt].y = *(int*)&h;
      e[cnt] = ek;
      cnt++;
    }
  }
#pragma unroll
  for (int k = 0; k < 4; k++)
    if (k < cnt) p[k] = atomicAdd(&cur[dst[e[k]]], 1);
#pragma unroll
  for (int k = 0; k < 4; k++)
    if (k < cnt) meta[p[k]] = mv[k];
}

// ---------------- weight prep: pack W into MFMA B-fragment layout, bf16 hi/lo ----
// B-frag for v_mfma_f32_16x16x32_bf16: lane l holds B[k=kt*32+8*(l>>4)+e][n=nt*16+(l&15)].
// nt=8 is the folded attention column (n==128 -> W_att).  Verified R11.
__global__ void prep_weights(const float* __restrict__ W_emb,
                             const float* __restrict__ W_att,
                             ushort* __restrict__ WBhi, ushort* __restrict__ WBlo) {
  int lane = threadIdx.x;               // 64
  int kt = blockIdx.x / 9, nt = blockIdx.x % 9;
  int part = blockIdx.y, l = blockIdx.z;
  int off = part ? 130 : 0;
  int g = lane >> 4, nn = lane & 15;
  int n = nt * 16 + nn;
  size_t base = (((size_t)((l * 2 + part) * 4 + kt) * 9 + nt) * 64 + lane) * 8;
#pragma unroll
  for (int e = 0; e < 8; e++) {
    int k = kt * 32 + 8 * g + e;
    float val = 0.f;
    if (nt < 8) val = W_emb[(size_t)(l * D + n) * EDGE_IN + off + k];
    else if (nn == 0) val = W_att[(size_t)l * EDGE_IN + off + k];
    ushort hi = f32_to_bf16(val);
    WBhi[base + e] = hi;
    WBlo[base + e] = f32_to_bf16(val - bf16_to_f32(hi));
  }
}

// Wrel: [L][2][128] for the edge kernel
__global__ void rel_prep(const float* __restrict__ W_emb, float* __restrict__ Wrel) {
  int d = threadIdx.x;          // 128
  int c = blockIdx.x;           // 0,1
  int l = blockIdx.y;
  Wrel[(l * 2 + c) * 128 + d] = W_emb[(size_t)(l * D + d) * EDGE_IN + 128 + c];
}

// ---------------- MFMA projections (+ folded attention dots) ----------------
// One block = 16 actors, 2 waves: wave 0 -> src (Ps16+a_s), wave 1 -> dst (Pd+a_d).
// fp32 recovered via bf16 hi/lo split: Ahi*Bhi + Alo*Bhi + Ahi*Blo. (verified R11)
__global__ __launch_bounds__(128) void proj_kernel(
    const float* __restrict__ feat, const ushort* __restrict__ WBhi,
    const ushort* __restrict__ WBlo, __half* __restrict__ Ps16,
    float* __restrict__ Pd, float* __restrict__ a_s, float* __restrict__ a_d,
    int n, int l) {
  __shared__ ushort Ahi[4][64][8];
  __shared__ ushort Alo[4][64][8];
  int i0 = blockIdx.x * 16;
  int tid = threadIdx.x;

  for (int t = tid; t < 512; t += 128) {
    int m = t >> 5;
    int k4 = t & 31;
    int gi = i0 + m;
    float4 v = (gi < n) ? ((const float4*)feat)[(size_t)gi * 32 + k4]
                        : make_float4(0.f, 0.f, 0.f, 0.f);
    int kt = k4 >> 3;
    int lanew = m + 16 * ((k4 >> 1) & 3);
    int eh = (k4 & 1) * 4;
    ushort hx = f32_to_bf16(v.x), hy = f32_to_bf16(v.y);
    ushort hz = f32_to_bf16(v.z), hw = f32_to_bf16(v.w);
    ushort4 h4 = make_ushort4(hx, hy, hz, hw);
    ushort4 l4 = make_ushort4(f32_to_bf16(v.x - bf16_to_f32(hx)),
                              f32_to_bf16(v.y - bf16_to_f32(hy)),
                              f32_to_bf16(v.z - bf16_to_f32(hz)),
                              f32_to_bf16(v.w - bf16_to_f32(hw)));
    *(ushort4*)&Ahi[kt][lanew][eh] = h4;
    *(ushort4*)&Alo[kt][lanew][eh] = l4;
  }
  __syncthreads();

  int w = tid >> 6;
  int lane = tid & 63;

  bf16x8 ah[4], al[4];
#pragma unroll
  for (int kt = 0; kt < 4; kt++) {
    ah[kt] = *(const bf16x8*)&Ahi[kt][lane][0];
    al[kt] = *(const bf16x8*)&Alo[kt][lane][0];
  }

  const ushort* bh = WBhi + (size_t)(l * 2 + w) * 4 * 9 * 64 * 8;
  const ushort* bl = WBlo + (size_t)(l * 2 + w) * 4 * 9 * 64 * 8;

  f32x4 acc[9];
#pragma unroll
  for (int i = 0; i < 9; i++) acc[i] = (f32x4){0.f, 0.f, 0.f, 0.f};

#pragma unroll
  for (int nt = 0; nt < 9; nt++) {
#pragma unroll
    for (int kt = 0; kt < 4; kt++) {
      size_t idx = (((size_t)kt * 9 + nt) * 64 + lane) * 8;
      bf16x8 bhv = *(const bf16x8*)&bh[idx];
      bf16x8 blv = *(const bf16x8*)&bl[idx];
      acc[nt] = __builtin_amdgcn_mfma_f32_16x16x32_bf16(ah[kt], bhv, acc[nt], 0, 0, 0);
      acc[nt] = __builtin_amdgcn_mfma_f32_16x16x32_bf16(al[kt], bhv, acc[nt], 0, 0, 0);
      acc[nt] = __builtin_amdgcn_mfma_f32_16x16x32_bf16(ah[kt], blv, acc[nt], 0, 0, 0);
    }
  }

  int col0 = lane & 15, rowg = lane >> 4;
  if (w == 0) {
#pragma unroll
    for (int nt = 0; nt < 8; nt++)
#pragma unroll
      for (int r = 0; r < 4; r++) {
        int gi = i0 + rowg * 4 + r;
        if (gi < n) Ps16[(size_t)gi * D + nt * 16 + col0] = __float2half(acc[nt][r]);
      }
    if (col0 == 0) {
#pragma unroll
      for (int r = 0; r < 4; r++) {
        int gi = i0 + rowg * 4 + r;
        if (gi < n) a_s[gi] = acc[8][r];
      }
    }
  } else {
#pragma unroll
    for (int nt = 0; nt < 8; nt++)
#pragma unroll
      for (int r = 0; r < 4; r++) {
        int gi = i0 + rowg * 4 + r;
        if (gi < n) Pd[(size_t)gi * D + nt * 16 + col0] = acc[nt][r];
      }
    if (col0 == 0) {
#pragma unroll
      for (int r = 0; r < 4; r++) {
        int gi = i0 + rowg * 4 + r;
        if (gi < n) a_d[gi] = acc[8][r];
      }
    }
  }
}

// ---------------- edge pass: one wave per dst ----------------
// Rel factored out (R12): acc = sum w*Ps[s]; rel term = Sx*wc0+Sy*wc1 in epilogue.
// meta is 8B {si, half2 rel}.
__global__ __launch_bounds__(256) void edge_kernel(
    const __half2* __restrict__ Ps, const float* __restrict__ Pd,
    const float* __restrict__ a_s, const float* __restrict__ a_d,
    const int2* __restrict__ meta, const int* __restrict__ offs,
    const float* __restrict__ Wrel, const float* __restrict__ W_att,
    float* __restrict__ out, int n, int l) {
  int wid = (blockIdx.x * blockDim.x + threadIdx.x) >> 6;
  if (wid >= n) return;
  int lane = threadIdx.x & 63;
  int d0 = 2 * lane;
  float wax = W_att[(size_t)l * EDGE_IN + 128];
  float way = W_att[(size_t)l * EDGE_IN + 129];
  float ad = a_d[wid];
  int p0 = offs[wid], p1 = offs[wid + 1];
  float m = -1e30f, lsum = 0.f, Sx = 0.f, Sy = 0.f;
  float accx = 0.f, accy = 0.f;
  for (int c0 = p0; c0 < p1; c0 += 64) {
    int cn = min(64, p1 - c0);
    int si = 0;
    float rx = 0.f, ry = 0.f, s = -1e30f;
    if (lane < cn) {
      int2 mt = meta[c0 + lane];
      si = mt.x;
      float2 rr = __half22float2(*(__half2*)&mt.y);
      rx = rr.x;
      ry = rr.y;
      float sc = a_s[si] + ad + rx * wax + ry * way;
      s = (sc > 0.f) ? sc : 0.2f * sc;
    }
    float cm = s;
#pragma unroll
    for (int o = 32; o; o >>= 1) cm = fmaxf(cm, __shfl_xor(cm, o, 64));
    float mnew = fmaxf(m, cm);
    float corr = __expf(m - mnew);
    float w = (lane < cn) ? __expf(s - mnew) : 0.f;
    float cw = w, cwx = w * rx, cwy = w * ry;
#pragma unroll
    for (int o = 32; o; o >>= 1) {
      cw += __shfl_xor(cw, o, 64);
      cwx += __shfl_xor(cwx, o, 64);
      cwy += __shfl_xor(cwy, o, 64);
    }
    lsum = lsum * corr + cw;
    Sx = Sx * corr + cwx;
    Sy = Sy * corr + cwy;
    accx *= corr;
    accy *= corr;
    m = mnew;
    int j = 0;
    for (; j + 8 <= cn; j += 8) {
      float2 f[8];
      float wj[8];
#pragma unroll
      for (int q = 0; q < 8; q++) {
        int sj = rl_i(si, j + q);
        wj[q] = rl_f(w, j + q);
        f[q] = __half22float2(Ps[(size_t)sj * 64 + lane]);
      }
#pragma unroll
      for (int q = 0; q < 8; q++) {
        accx += wj[q] * f[q].x;
        accy += wj[q] * f[q].y;
      }
    }
    if (j < cn) {
      float2 f[8];
      float wj[8];
      int r = cn - j;  // 1..7
#pragma unroll
      for (int q = 0; q < 8; q++) {
        if (q < r) {
          int sj = rl_i(si, j + q);
          wj[q] = rl_f(w, j + q);
          f[q] = __half22float2(Ps[(size_t)sj * 64 + lane]);
        }
      }
#pragma unroll
      for (int q = 0; q < 8; q++) {
        if (q < r) {
          accx += wj[q] * f[q].x;
          accy += wj[q] * f[q].y;
        }
      }
    }
  }
  float2 o2 = make_float2(0.f, 0.f);
  if (p1 > p0) {
    const float2 wc0 = *(const float2*)&Wrel[(l * 2 + 0) * 128 + d0];
    const float2 wc1 = *(const float2*)&Wrel[(l * 2 + 1) * 128 + d0];
    float inv = 1.0f / lsum;
    float2 pd = *(const float2*)&Pd[(size_t)wid * D + d0];
    accx += Sx * wc0.x + Sy * wc1.x;
    accy += Sx * wc0.y + Sy * wc1.y;
    o2.x = fmaxf(accx * inv + pd.x, 0.f);
    o2.y = fmaxf(accy * inv + pd.y, 0.f);
  }
  *(float2*)&out[(size_t)wid * D + d0] = o2;
}

extern "C" void kernel_launch(void* const* d_in, const int* in_sizes, int n_in,
                              void* d_out, int out_size, void* d_ws, size_t ws_size,
                              hipStream_t stream) {
  const float* actor = (const float*)d_in[0];
  const float* rel   = (const float*)d_in[1];
  const float* W_att = (const float*)d_in[2];
  const float* W_emb = (const float*)d_in[3];
  const int* srcIdx  = (const int*)d_in[4];
  const int* dstIdx  = (const int*)d_in[5];
  int n  = in_sizes[0] / D;          // 50000
  int ne = in_sizes[4];              // 800000
  int Lnum = in_sizes[2] / EDGE_IN;  // 2
  float* fout_last = (float*)d_out;

  float* ws = (float*)d_ws;
  size_t o = 0;
  int2* meta = (int2*)ws; o += 2 * (size_t)ne;
  size_t wbN = (size_t)Lnum * 2 * 4 * 9 * 64 * 8;  // ushorts per buffer
  ushort* WBhi = (ushort*)(ws + o); o += (wbN + 1) / 2;
  ushort* WBlo = (ushort*)(ws + o); o += (wbN + 1) / 2;
  float* Wre = ws + o; o += (size_t)Lnum * 2 * 128;
  float* Pd  = ws + o; o += (size_t)n * D;
  float* a_s = ws + o; o += (size_t)n + 64;
  float* a_d = ws + o; o += (size_t)n + 64;
  __half* Ps16 = (__half*)(ws + o); o += (size_t)n * D / 2;
  int* ibuf = (int*)(ws + o);
  size_t io = 0;
  int* deg  = ibuf + io; io += n + 64;
  int* offs = ibuf + io; io += n + 64;
  int* cur  = ibuf + io; io += n + 64;
  int* bsum = ibuf + io; io += 256;

  int nb = (n + 1023) / 1024;
  int nbe = (ne + 1023) / 1024;  // ILP-4 edge blocks

  zero_int<<<(n + 255) / 256, 256, 0, stream>>>(deg, n);
  hist_kernel<<<nbe, 256, 0, stream>>>(dstIdx, deg, ne);
  scan_part<<<nb, 256, 0, stream>>>(deg, bsum, n);
  scan_bsums<<<1, 256, 0, stream>>>(bsum, nb);
  scan_final<<<nb, 256, 0, stream>>>(deg, bsum, offs, cur, n, ne);
  scatter_kernel<<<nbe, 256, 0, stream>>>(dstIdx, srcIdx, (const float2*)rel, cur, meta, ne);
  prep_weights<<<dim3(36, 2, Lnum), 64, 0, stream>>>(W_emb, W_att, WBhi, WBlo);
  rel_prep<<<dim3(2, Lnum), 128, 0, stream>>>(W_emb, Wre);

  const float* fin = actor;
  int nt16 = (n + 15) / 16;
  for (int l = 0; l < Lnum; l++) {
    proj_kernel<<<nt16, 128, 0, stream>>>(fin, WBhi, WBlo, Ps16, Pd, a_s, a_d, n, l);
    edge_kernel<<<(n + 3) / 4, 256, 0, stream>>>((const __half2*)Ps16, Pd, a_s, a_d, meta,
                                                 offs, Wre, W_att, fout_last, n, l);
    fin = fout_last;
  }
}

// Round 17
// 327.095 us; speedup vs baseline: 1.0714x; 1.0714x over previous
//
#include <hip/hip_runtime.h>
#include <hip/hip_fp16.h>

#define D 128
#define EDGE_IN 258

typedef __attribute__((ext_vector_type(8))) short bf16x8;
typedef __attribute__((ext_vector_type(4))) float f32x4;

__device__ __forceinline__ ushort f32_to_bf16(float f) {
  unsigned u = __float_as_uint(f);
  unsigned r = (u + 0x7FFFu + ((u >> 16) & 1u)) >> 16;  // RNE
  return (ushort)r;
}
__device__ __forceinline__ float bf16_to_f32(ushort h) {
  return __uint_as_float(((unsigned)h) << 16);
}

// ---------------- CSR build ----------------
__global__ void zero_int(int* __restrict__ p, int n) {
  int i = blockIdx.x * blockDim.x + threadIdx.x;
  if (i < n) p[i] = 0;
}

// ILP-4 atomic chains
__global__ void hist_kernel(const int* __restrict__ dst, int* __restrict__ deg, int ne) {
  int base = blockIdx.x * 1024 + threadIdx.x;
#pragma unroll
  for (int k = 0; k < 4; k++) {
    int e = base + k * 256;
    if (e < ne) atomicAdd(&deg[dst[e]], 1);
  }
}

__global__ __launch_bounds__(256) void scan_part(const int* __restrict__ deg,
                                                 int* __restrict__ bsum, int n) {
  __shared__ int red[256];
  int b = blockIdx.x, tid = threadIdx.x;
  int base = b * 1024 + tid * 4;
  int s = 0;
#pragma unroll
  for (int j = 0; j < 4; j++) { int idx = base + j; if (idx < n) s += deg[idx]; }
  red[tid] = s;
  __syncthreads();
  for (int off = 128; off; off >>= 1) {
    if (tid < off) red[tid] += red[tid + off];
    __syncthreads();
  }
  if (tid == 0) bsum[b] = red[0];
}

__global__ __launch_bounds__(256) void scan_bsums(int* __restrict__ bsum, int nb) {
  __shared__ int part[256];
  int tid = threadIdx.x;
  int v = (tid < nb) ? bsum[tid] : 0;
  part[tid] = v;
  __syncthreads();
  for (int off = 1; off < 256; off <<= 1) {
    int t = (tid >= off) ? part[tid - off] : 0;
    __syncthreads();
    part[tid] += t;
    __syncthreads();
  }
  if (tid < nb) bsum[tid] = (tid == 0) ? 0 : part[tid - 1];  // exclusive
}

__global__ __launch_bounds__(256) void scan_final(const int* __restrict__ deg,
                                                  const int* __restrict__ bsumex,
                                                  int* __restrict__ offs,
                                                  int* __restrict__ cur, int n, int ne) {
  __shared__ int part[256];
  int b = blockIdx.x, tid = threadIdx.x;
  int base = b * 1024 + tid * 4;
  int v[4];
  int s = 0;
#pragma unroll
  for (int j = 0; j < 4; j++) {
    int idx = base + j;
    v[j] = (idx < n) ? deg[idx] : 0;
    s += v[j];
  }
  part[tid] = s;
  __syncthreads();
  for (int off = 1; off < 256; off <<= 1) {
    int t = (tid >= off) ? part[tid - off] : 0;
    __syncthreads();
    part[tid] += t;
    __syncthreads();
  }
  int run = bsumex[b] + ((tid == 0) ? 0 : part[tid - 1]);
#pragma unroll
  for (int j = 0; j < 4; j++) {
    int idx = base + j;
    if (idx < n) { offs[idx] = run; cur[idx] = run; run += v[j]; }
  }
  if (b == 0 && tid == 0) offs[n] = ne;
}

// meta 8B/edge {si, half2 rel}. NOTE (R15): random-store traffic is per-64B-LINE,
// so 16->8B didn't halve WRITE; scatter floor is ~line-traffic-bound. Kept for
// the edge-side fetch savings.
__global__ void scatter_kernel(const int* __restrict__ dst, const int* __restrict__ srcIdx,
                               const float2* __restrict__ rel, int* __restrict__ cur,
                               int2* __restrict__ meta, int ne) {
  int base = blockIdx.x * 1024 + threadIdx.x;
  int e[4], p[4];
  int2 mv[4];
  int cnt = 0;
#pragma unroll
  for (int k = 0; k < 4; k++) {
    int ek = base + k * 256;
    if (ek < ne) {
      float2 r = rel[ek];
      __half2 h = __floats2half2_rn(r.x, r.y);
      mv[cnt].x = srcIdx[ek];
      mv[cnt].y = *(int*)&h;
      e[cnt] = ek;
      cnt++;
    }
  }
#pragma unroll
  for (int k = 0; k < 4; k++)
    if (k < cnt) p[k] = atomicAdd(&cur[dst[e[k]]], 1);
#pragma unroll
  for (int k = 0; k < 4; k++)
    if (k < cnt) meta[p[k]] = mv[k];
}

// ---------------- weight prep: pack W into MFMA B-fragment layout, bf16 hi/lo ----
// B-frag for v_mfma_f32_16x16x32_bf16: lane l holds B[k=kt*32+8*(l>>4)+e][n=nt*16+(l&15)].
// nt=8 is the folded attention column (n==128 -> W_att).  Verified R11.
__global__ void prep_weights(const float* __restrict__ W_emb,
                             const float* __restrict__ W_att,
                             ushort* __restrict__ WBhi, ushort* __restrict__ WBlo) {
  int lane = threadIdx.x;               // 64
  int kt = blockIdx.x / 9, nt = blockIdx.x % 9;
  int part = blockIdx.y, l = blockIdx.z;
  int off = part ? 130 : 0;
  int g = lane >> 4, nn = lane & 15;
  int n = nt * 16 + nn;
  size_t base = (((size_t)((l * 2 + part) * 4 + kt) * 9 + nt) * 64 + lane) * 8;
#pragma unroll
  for (int e = 0; e < 8; e++) {
    int k = kt * 32 + 8 * g + e;
    float val = 0.f;
    if (nt < 8) val = W_emb[(size_t)(l * D + n) * EDGE_IN + off + k];
    else if (nn == 0) val = W_att[(size_t)l * EDGE_IN + off + k];
    ushort hi = f32_to_bf16(val);
    WBhi[base + e] = hi;
    WBlo[base + e] = f32_to_bf16(val - bf16_to_f32(hi));
  }
}

// Wrel: [L][2][128] for the edge kernel
__global__ void rel_prep(const float* __restrict__ W_emb, float* __restrict__ Wrel) {
  int d = threadIdx.x;          // 128
  int c = blockIdx.x;           // 0,1
  int l = blockIdx.y;
  Wrel[(l * 2 + c) * 128 + d] = W_emb[(size_t)(l * D + d) * EDGE_IN + 128 + c];
}

// ---------------- MFMA projections (+ folded attention dots) ----------------
// One block = 16 actors, 2 waves: wave 0 -> src (Ps16+a_s), wave 1 -> dst (Pd+a_d).
// fp32 recovered via bf16 hi/lo split: Ahi*Bhi + Alo*Bhi + Ahi*Blo. (verified R11)
__global__ __launch_bounds__(128) void proj_kernel(
    const float* __restrict__ feat, const ushort* __restrict__ WBhi,
    const ushort* __restrict__ WBlo, __half* __restrict__ Ps16,
    float* __restrict__ Pd, float* __restrict__ a_s, float* __restrict__ a_d,
    int n, int l) {
  __shared__ ushort Ahi[4][64][8];
  __shared__ ushort Alo[4][64][8];
  int i0 = blockIdx.x * 16;
  int tid = threadIdx.x;

  for (int t = tid; t < 512; t += 128) {
    int m = t >> 5;
    int k4 = t & 31;
    int gi = i0 + m;
    float4 v = (gi < n) ? ((const float4*)feat)[(size_t)gi * 32 + k4]
                        : make_float4(0.f, 0.f, 0.f, 0.f);
    int kt = k4 >> 3;
    int lanew = m + 16 * ((k4 >> 1) & 3);
    int eh = (k4 & 1) * 4;
    ushort hx = f32_to_bf16(v.x), hy = f32_to_bf16(v.y);
    ushort hz = f32_to_bf16(v.z), hw = f32_to_bf16(v.w);
    ushort4 h4 = make_ushort4(hx, hy, hz, hw);
    ushort4 l4 = make_ushort4(f32_to_bf16(v.x - bf16_to_f32(hx)),
                              f32_to_bf16(v.y - bf16_to_f32(hy)),
                              f32_to_bf16(v.z - bf16_to_f32(hz)),
                              f32_to_bf16(v.w - bf16_to_f32(hw)));
    *(ushort4*)&Ahi[kt][lanew][eh] = h4;
    *(ushort4*)&Alo[kt][lanew][eh] = l4;
  }
  __syncthreads();

  int w = tid >> 6;
  int lane = tid & 63;

  bf16x8 ah[4], al[4];
#pragma unroll
  for (int kt = 0; kt < 4; kt++) {
    ah[kt] = *(const bf16x8*)&Ahi[kt][lane][0];
    al[kt] = *(const bf16x8*)&Alo[kt][lane][0];
  }

  const ushort* bh = WBhi + (size_t)(l * 2 + w) * 4 * 9 * 64 * 8;
  const ushort* bl = WBlo + (size_t)(l * 2 + w) * 4 * 9 * 64 * 8;

  f32x4 acc[9];
#pragma unroll
  for (int i = 0; i < 9; i++) acc[i] = (f32x4){0.f, 0.f, 0.f, 0.f};

#pragma unroll
  for (int nt = 0; nt < 9; nt++) {
#pragma unroll
    for (int kt = 0; kt < 4; kt++) {
      size_t idx = (((size_t)kt * 9 + nt) * 64 + lane) * 8;
      bf16x8 bhv = *(const bf16x8*)&bh[idx];
      bf16x8 blv = *(const bf16x8*)&bl[idx];
      acc[nt] = __builtin_amdgcn_mfma_f32_16x16x32_bf16(ah[kt], bhv, acc[nt], 0, 0, 0);
      acc[nt] = __builtin_amdgcn_mfma_f32_16x16x32_bf16(al[kt], bhv, acc[nt], 0, 0, 0);
      acc[nt] = __builtin_amdgcn_mfma_f32_16x16x32_bf16(ah[kt], blv, acc[nt], 0, 0, 0);
    }
  }

  int col0 = lane & 15, rowg = lane >> 4;
  if (w == 0) {
#pragma unroll
    for (int nt = 0; nt < 8; nt++)
#pragma unroll
      for (int r = 0; r < 4; r++) {
        int gi = i0 + rowg * 4 + r;
        if (gi < n) Ps16[(size_t)gi * D + nt * 16 + col0] = __float2half(acc[nt][r]);
      }
    if (col0 == 0) {
#pragma unroll
      for (int r = 0; r < 4; r++) {
        int gi = i0 + rowg * 4 + r;
        if (gi < n) a_s[gi] = acc[8][r];
      }
    }
  } else {
#pragma unroll
    for (int nt = 0; nt < 8; nt++)
#pragma unroll
      for (int r = 0; r < 4; r++) {
        int gi = i0 + rowg * 4 + r;
        if (gi < n) Pd[(size_t)gi * D + nt * 16 + col0] = acc[nt][r];
      }
    if (col0 == 0) {
#pragma unroll
      for (int r = 0; r < 4; r++) {
        int gi = i0 + rowg * 4 + r;
        if (gi < n) a_d[gi] = acc[8][r];
      }
    }
  }
}

// ---------------- edge pass: 4 dst per wave, 16 lanes/dst, 8 dims/lane ----------
// R16 restructure: avg degree = 16, so the old 1-dst/wave layout left 48/64 lanes
// idle in the score phase and ran 6-step 64-lane butterflies. Now:
//  - Phase A: all 64 lanes score (4 dst at once); segmented 4-step shfl_xor
//    reductions (masks 8..1 stay inside 16-lane groups).
//  - Phase B: per edge one uint4 (16B) per lane = whole 256B Ps row per group;
//    si/w broadcast via per-lane-source __shfl (ds_bpermute); 4 edges in flight
//    per group = 16 outstanding gathers/wave. Lanes >= cn carry w=0,si=0 so the
//    4-wide loop needs no tail guards (w=0 annihilates padded rows).
__global__ __launch_bounds__(256) void edge_kernel(
    const __half* __restrict__ Ps, const float* __restrict__ Pd,
    const float* __restrict__ a_s, const float* __restrict__ a_d,
    const int2* __restrict__ meta, const int* __restrict__ offs,
    const float* __restrict__ Wrel, const float* __restrict__ W_att,
    float* __restrict__ out, int n, int l) {
  int wave = (blockIdx.x * blockDim.x + threadIdx.x) >> 6;
  int lane = threadIdx.x & 63;
  int g = lane >> 4, lg = lane & 15;
  int v = wave * 4 + g;
  bool valid = v < n;
  int p0 = 0, p1 = 0;
  if (valid) { p0 = offs[v]; p1 = offs[v + 1]; }
  float wax = W_att[(size_t)l * EDGE_IN + 128];
  float way = W_att[(size_t)l * EDGE_IN + 129];
  float ad = valid ? a_d[v] : 0.f;
  float m = -1e30f, lsum = 0.f, Sx = 0.f, Sy = 0.f;
  float acc[8];
#pragma unroll
  for (int i = 0; i < 8; i++) acc[i] = 0.f;
  int gbase = g * 16;
  int dbase = lg * 8;

  for (int c0 = p0; c0 < p1; c0 += 16) {
    int cn = min(16, p1 - c0);
    int si = 0;
    float rx = 0.f, ry = 0.f, s = -1e30f;
    if (lg < cn) {
      int2 mt = meta[c0 + lg];
      si = mt.x;
      float2 rr = __half22float2(*(__half2*)&mt.y);
      rx = rr.x;
      ry = rr.y;
      float sc = a_s[si] + ad + rx * wax + ry * way;
      s = (sc > 0.f) ? sc : 0.2f * sc;
    }
    // segmented (16-lane) reductions
    float cm = s;
#pragma unroll
    for (int o = 8; o; o >>= 1) cm = fmaxf(cm, __shfl_xor(cm, o, 64));
    float mnew = fmaxf(m, cm);
    float corr = __expf(m - mnew);
    float w = (lg < cn) ? __expf(s - mnew) : 0.f;
    float cw = w, cwx = w * rx, cwy = w * ry;
#pragma unroll
    for (int o = 8; o; o >>= 1) {
      cw += __shfl_xor(cw, o, 64);
      cwx += __shfl_xor(cwx, o, 64);
      cwy += __shfl_xor(cwy, o, 64);
    }
    lsum = lsum * corr + cw;
    Sx = Sx * corr + cwx;
    Sy = Sy * corr + cwy;
#pragma unroll
    for (int i = 0; i < 8; i++) acc[i] *= corr;
    m = mnew;

    // Phase B: unguarded 4-deep (padded lanes have w=0 -> contribute 0)
    for (int j = 0; j < cn; j += 4) {
      uint4 h[4];
      float wj[4];
#pragma unroll
      for (int q = 0; q < 4; q++) {
        int sj = __shfl(si, gbase + j + q, 64);
        wj[q] = __shfl(w, gbase + j + q, 64);
        h[q] = *(const uint4*)&Ps[(size_t)sj * D + dbase];
      }
#pragma unroll
      for (int q = 0; q < 4; q++) {
        float2 f0 = __half22float2(*(__half2*)&h[q].x);
        float2 f1 = __half22float2(*(__half2*)&h[q].y);
        float2 f2 = __half22float2(*(__half2*)&h[q].z);
        float2 f3 = __half22float2(*(__half2*)&h[q].w);
        acc[0] += wj[q] * f0.x;
        acc[1] += wj[q] * f0.y;
        acc[2] += wj[q] * f1.x;
        acc[3] += wj[q] * f1.y;
        acc[4] += wj[q] * f2.x;
        acc[5] += wj[q] * f2.y;
        acc[6] += wj[q] * f3.x;
        acc[7] += wj[q] * f3.y;
      }
    }
  }

  float res[8];
#pragma unroll
  for (int i = 0; i < 8; i++) res[i] = 0.f;
  if (valid && p1 > p0) {
    float inv = 1.0f / lsum;
    const float4* wc0p = (const float4*)&Wrel[(size_t)(l * 2 + 0) * 128 + dbase];
    const float4* wc1p = (const float4*)&Wrel[(size_t)(l * 2 + 1) * 128 + dbase];
    const float4* pdp = (const float4*)&Pd[(size_t)v * D + dbase];
    float4 w0a = wc0p[0], w0b = wc0p[1];
    float4 w1a = wc1p[0], w1b = wc1p[1];
    float4 pda = pdp[0], pdb = pdp[1];
    float c0v[8] = {w0a.x, w0a.y, w0a.z, w0a.w, w0b.x, w0b.y, w0b.z, w0b.w};
    float c1v[8] = {w1a.x, w1a.y, w1a.z, w1a.w, w1b.x, w1b.y, w1b.z, w1b.w};
    float pdv[8] = {pda.x, pda.y, pda.z, pda.w, pdb.x, pdb.y, pdb.z, pdb.w};
#pragma unroll
    for (int i = 0; i < 8; i++) {
      float a = acc[i] + Sx * c0v[i] + Sy * c1v[i];
      res[i] = fmaxf(a * inv + pdv[i], 0.f);
    }
  }
  if (valid) {
    float4* op = (float4*)&out[(size_t)v * D + dbase];
    op[0] = make_float4(res[0], res[1], res[2], res[3]);
    op[1] = make_float4(res[4], res[5], res[6], res[7]);
  }
}

extern "C" void kernel_launch(void* const* d_in, const int* in_sizes, int n_in,
                              void* d_out, int out_size, void* d_ws, size_t ws_size,
                              hipStream_t stream) {
  const float* actor = (const float*)d_in[0];
  const float* rel   = (const float*)d_in[1];
  const float* W_att = (const float*)d_in[2];
  const float* W_emb = (const float*)d_in[3];
  const int* srcIdx  = (const int*)d_in[4];
  const int* dstIdx  = (const int*)d_in[5];
  int n  = in_sizes[0] / D;          // 50000
  int ne = in_sizes[4];              // 800000
  int Lnum = in_sizes[2] / EDGE_IN;  // 2
  float* fout_last = (float*)d_out;

  float* ws = (float*)d_ws;
  size_t o = 0;
  int2* meta = (int2*)ws; o += 2 * (size_t)ne;
  size_t wbN = (size_t)Lnum * 2 * 4 * 9 * 64 * 8;  // ushorts per buffer
  ushort* WBhi = (ushort*)(ws + o); o += (wbN + 1) / 2;
  ushort* WBlo = (ushort*)(ws + o); o += (wbN + 1) / 2;
  float* Wre = ws + o; o += (size_t)Lnum * 2 * 128;
  float* Pd  = ws + o; o += (size_t)n * D;
  float* a_s = ws + o; o += (size_t)n + 64;
  float* a_d = ws + o; o += (size_t)n + 64;
  __half* Ps16 = (__half*)(ws + o); o += (size_t)n * D / 2;
  int* ibuf = (int*)(ws + o);
  size_t io = 0;
  int* deg  = ibuf + io; io += n + 64;
  int* offs = ibuf + io; io += n + 64;
  int* cur  = ibuf + io; io += n + 64;
  int* bsum = ibuf + io; io += 256;

  int nb = (n + 1023) / 1024;
  int nbe = (ne + 1023) / 1024;  // ILP-4 edge blocks

  zero_int<<<(n + 255) / 256, 256, 0, stream>>>(deg, n);
  hist_kernel<<<nbe, 256, 0, stream>>>(dstIdx, deg, ne);
  scan_part<<<nb, 256, 0, stream>>>(deg, bsum, n);
  scan_bsums<<<1, 256, 0, stream>>>(bsum, nb);
  scan_final<<<nb, 256, 0, stream>>>(deg, bsum, offs, cur, n, ne);
  scatter_kernel<<<nbe, 256, 0, stream>>>(dstIdx, srcIdx, (const float2*)rel, cur, meta, ne);
  prep_weights<<<dim3(36, 2, Lnum), 64, 0, stream>>>(W_emb, W_att, WBhi, WBlo);
  rel_prep<<<dim3(2, Lnum), 128, 0, stream>>>(W_emb, Wre);

  const float* fin = actor;
  int nt16 = (n + 15) / 16;
  int nbedge = (n + 15) / 16;  // 16 dst per block (4 waves x 4 dst)
  for (int l = 0; l < Lnum; l++) {
    proj_kernel<<<nt16, 128, 0, stream>>>(fin, WBhi, WBlo, Ps16, Pd, a_s, a_d, n, l);
    edge_kernel<<<nbedge, 256, 0, stream>>>(Ps16, Pd, a_s, a_d, meta,
                                            offs, Wre, W_att, fout_last, n, l);
    fin = fout_last;
  }
}